// Round 7
// baseline (280.290 us; speedup 1.0000x reference)
//
#include <hip/hip_runtime.h>

// Integrate-and-fire, soft reset, T=128 sequential scan per row. rows = 262144.
//
// Round-6 postmortem: previous register kernel only read 8 float4 = 32 of the
// 128 timesteps (a row is 32 float4s) -> t>=32 spikes never written, absmax 1.0.
// This version: register DOUBLE-BUFFER over 4 chunks of 8 float4 (32 steps).
// Prefetch chunk c+1 (8 independent dwordx4 loads) while scanning chunk c in
// registers; stream float4 stores. No LDS, no barriers. ~90 VGPR -> 128-VGPR
// bucket -> 16 waves/CU; each wave keeps ~8 KB of loads in flight continuously.
// All buffer indices are compile-time constants (full unroll) -> registers,
// no scratch.

#define T_STEPS 128

__global__ __launch_bounds__(256) void if_scan_regs_kernel(
    const float* __restrict__ x,      // [rows, T]
    const float* __restrict__ v0,     // [rows]
    const float* __restrict__ thr_p,  // [1]
    float* __restrict__ spikes,       // [rows, T]
    float* __restrict__ vfin,         // [rows]
    int nrows)
{
    const int row = blockIdx.x * 256 + threadIdx.x;
    if (row >= nrows) return;

    const float4* __restrict__ xr = reinterpret_cast<const float4*>(
        x + (size_t)row * T_STEPS);           // 32 float4 per row
    float4* __restrict__ sr = reinterpret_cast<float4*>(
        spikes + (size_t)row * T_STEPS);

    float4 buf[2][8];

    // Prefetch chunk 0 (float4 0..7 -> t 0..31).
    #pragma unroll
    for (int k = 0; k < 8; ++k) buf[0][k] = xr[k];

    float v = v0[row];
    const float thr = thr_p[0];

    #pragma unroll
    for (int c = 0; c < 4; ++c) {             // chunk c: float4 c*8 .. c*8+7
        const int cur = c & 1;
        const int nxt = cur ^ 1;
        if (c < 3) {
            // Prefetch next chunk's 8 loads before consuming current chunk.
            #pragma unroll
            for (int k = 0; k < 8; ++k) buf[nxt][k] = xr[(c + 1) * 8 + k];
        }
        #pragma unroll
        for (int k = 0; k < 8; ++k) {
            const float4 xv = buf[cur][k];
            float4 sp;
            v += xv.x; { const bool f = v >= thr; sp.x = f ? 1.0f : 0.0f; v = f ? v - thr : v; }
            v += xv.y; { const bool f = v >= thr; sp.y = f ? 1.0f : 0.0f; v = f ? v - thr : v; }
            v += xv.z; { const bool f = v >= thr; sp.z = f ? 1.0f : 0.0f; v = f ? v - thr : v; }
            v += xv.w; { const bool f = v >= thr; sp.w = f ? 1.0f : 0.0f; v = f ? v - thr : v; }
            sr[c * 8 + k] = sp;               // fire-and-forget store
        }
    }

    vfin[row] = v;
}

extern "C" void kernel_launch(void* const* d_in, const int* in_sizes, int n_in,
                              void* d_out, int out_size, void* d_ws, size_t ws_size,
                              hipStream_t stream) {
    const float* x     = (const float*)d_in[0];   // input_spikes [64,4096,128]
    const float* v0    = (const float*)d_in[1];   // states [64,4096]
    const float* thr_p = (const float*)d_in[2];   // threshold scalar

    const int nrows = in_sizes[1];                // 262144
    float* spikes = (float*)d_out;
    float* vfin   = (float*)d_out + (size_t)nrows * T_STEPS;

    const int blocks = (nrows + 255) / 256;       // 1024
    if_scan_regs_kernel<<<blocks, 256, 0, stream>>>(x, v0, thr_p, spikes, vfin, nrows);
}